// Round 15
// baseline (195.411 us; speedup 1.0000x reference)
//
#include <hip/hip_runtime.h>
#include <hip/hip_bf16.h>
#include <stdint.h>

// Decoder block B=256,T=256,D=96,H=6,E=16,DFF=384. f32 in/out, f32 acc.
// Round 26 = r23 structure with launch_bounds(256,8) -> (256,7).
// Post-mortems r23/r24/r25: at 8 waves/EU the 64-reg unified budget splits
// 32 VGPR + 32 AGPR and the FF phase's non-accumulator state (ah12+af12+
// ffp6+addr) can't fit 32 arch VGPRs -> structural spill regardless of diet
// (3 attempts). (256,7) gives ~72 regs (~56V+16A) which fits; 7 resident
// blocks vs 8 blocks/CU of work -> dispatcher backfills, tail ~1 block.
// r25's L2-parking reverted (x1 lines evicted before readback: +32MB HBM).
// Canary: VGPR_Count no longer 32; WRITE ~24.6MB. k_attn_fused = r22 exact.
// Noise: jax threefry2x32 PARTITIONABLE scheme (verified round 5).

#define B_    256
#define T_    256
#define D_    96
#define H_    6
#define E_    16
#define DFF_  384
#define BT_   (B_*T_)        // 65536
#define NTOK_ (BT_*D_)       // 6291456
#define WPN_  (96*96)        // 9216
#define W1N_  (96*384)       // 36864
#define W2N_  (384*96)       // 36864
#define WTOT_ (WPN_+W1N_+W2N_)  // 82944 elems

typedef __hip_bfloat16 bf16;
typedef __attribute__((ext_vector_type(8))) short v8s;
typedef __attribute__((ext_vector_type(4))) short v4s;
typedef __attribute__((ext_vector_type(4))) float v4f;

// compiler-only memory fence: stops reordering of LDS ops across it.
// HW executes DS ops of a wave in order, so this suffices for wave-private
// cross-lane LDS communication (no s_barrier cost).
__device__ __forceinline__ void wfence(){ __asm__ volatile("" ::: "memory"); }

__host__ __device__ inline uint32_t rotl32(uint32_t x, int r){ return (x<<r)|(x>>(32-r)); }

__host__ __device__ inline void tf2x32(uint32_t k0, uint32_t k1, uint32_t& x0, uint32_t& x1){
  uint32_t ks2 = k0 ^ k1 ^ 0x1BD11BDAu;
  x0 += k0; x1 += k1;
#define TF_R(r) { x0 += x1; x1 = rotl32(x1, r); x1 ^= x0; }
  TF_R(13) TF_R(15) TF_R(26) TF_R(6)
  x0 += k1;  x1 += ks2 + 1u;
  TF_R(17) TF_R(29) TF_R(16) TF_R(24)
  x0 += ks2; x1 += k0 + 2u;
  TF_R(13) TF_R(15) TF_R(26) TF_R(6)
  x0 += k0;  x1 += k1 + 3u;
  TF_R(17) TF_R(29) TF_R(16) TF_R(24)
  x0 += k1;  x1 += ks2 + 4u;
  TF_R(13) TF_R(15) TF_R(26) TF_R(6)
  x0 += ks2; x1 += k0 + 5u;
#undef TF_R
}

// XLA f32 ErfInv, fast log path: -log1p(-x^2) == -ln2*log2((1-x)(1+x))
__device__ __forceinline__ float erfinv32(float x){
  float w = -0.69314718056f * __log2f((1.0f - x) * (1.0f + x));
  float p;
  if (w < 5.0f) {
    w -= 2.5f;
    p = 2.81022636e-08f;
    p = fmaf(p, w, 3.43273939e-07f);
    p = fmaf(p, w, -3.5233877e-06f);
    p = fmaf(p, w, -4.39150654e-06f);
    p = fmaf(p, w, 0.00021858087f);
    p = fmaf(p, w, -0.00125372503f);
    p = fmaf(p, w, -0.00417768164f);
    p = fmaf(p, w, 0.246640727f);
    p = fmaf(p, w, 1.50140941f);
  } else {
    w = sqrtf(w) - 3.0f;
    p = -0.000200214257f;
    p = fmaf(p, w, 0.000100950558f);
    p = fmaf(p, w, 0.00134934322f);
    p = fmaf(p, w, -0.00367342844f);
    p = fmaf(p, w, 0.00573950773f);
    p = fmaf(p, w, -0.0076224613f);
    p = fmaf(p, w, 0.00943887047f);
    p = fmaf(p, w, 1.00167406f);
    p = fmaf(p, w, 2.83297682f);
  }
  return p * x;
}

__device__ __forceinline__ float jax_normal(uint32_t k0, uint32_t k1, uint32_t j){
  uint32_t x0 = 0u, x1 = j;
  tf2x32(k0, k1, x0, x1);
  uint32_t bits = x0 ^ x1;
  float f = __uint_as_float((bits >> 9) | 0x3F800000u) - 1.0f;
  const float lo = -0.99999994f;
  float u = fmaxf(lo, fmaf(f, 2.0f, lo));
  return 1.41421356f * erfinv32(u);
}

__device__ __forceinline__ float blo(uint32_t u){ return __uint_as_float(u << 16); }
__device__ __forceinline__ float bhi(uint32_t u){ return __uint_as_float(u & 0xFFFF0000u); }
__device__ __forceinline__ uint16_t f2b(float f){
  union { bf16 h; uint16_t u; } x; x.h = __float2bfloat16(f); return x.u;
}
__device__ __forceinline__ uint32_t packbf(float a, float b){
  return (uint32_t)f2b(a) | ((uint32_t)f2b(b) << 16);
}
__device__ __forceinline__ v4s pack4(float a, float b, float c, float d){
  uint64_t both = ((uint64_t)packbf(c, d) << 32) | (uint64_t)packbf(a, b);
  v4s r; __builtin_memcpy(&r, &both, 8); return r;
}

// K=16 bf16 MFMA (v_mfma_f32_16x16x16_bf16): builtin name varies by ROCm.
__device__ __forceinline__ v4f mfma16(v4s a, v4s b, v4f c){
#if __has_builtin(__builtin_amdgcn_mfma_f32_16x16x16_bf16)
  return __builtin_amdgcn_mfma_f32_16x16x16_bf16(a, b, c, 0, 0, 0);
#elif __has_builtin(__builtin_amdgcn_mfma_f32_16x16x16bf16_1k)
  return __builtin_amdgcn_mfma_f32_16x16x16bf16_1k(a, b, c, 0, 0, 0);
#else
  v4f d;
  asm volatile("v_mfma_f32_16x16x16_bf16 %0, %1, %2, %3"
               : "=v"(d) : "v"(a), "v"(b), "v"(c));
  return d;
#endif
}

// =================== K_A: prep-fold + LN1 + MFMA QKV + MFMA flash ===========
__global__ __launch_bounds__(256, 4)
void k_attn_fused(const float* __restrict__ x,
                  const float* __restrict__ Wq, const float* __restrict__ Wk,
                  const float* __restrict__ Wv,
                  const float* __restrict__ g1, const float* __restrict__ bln1,
                  bf16* __restrict__ o_ws,
                  const float* __restrict__ Wp, const float* __restrict__ W1,
                  const float* __restrict__ W2, bf16* __restrict__ wbuf)
{
  __shared__ __align__(16) uint16_t hts[64*104];   // LN tile; Pb aliases (wave-private rows)
  __shared__ __align__(16) uint32_t wpl[48][52];   // head W pairs (RO after stage)
  __shared__ __align__(16) uint16_t Ks[256][16];   // k rows, 16 e-cols, 32B stride
  __shared__ __align__(16) uint16_t Vt[16][264];   // V^T[e][s]

  const int tid  = threadIdx.x;
  const int bh   = blockIdx.x;
  const int b    = bh / H_, h = bh % H_;
  const int w    = tid >> 6;
  const int lane = tid & 63;
  const int quad = lane >> 4;
  const int l15  = lane & 15;

  // ---- folded k_prep: 54 weight elems per block -> wbuf fragment-major ----
  if (tid < 54) {
    int id = bh*54 + tid;   // < 82944 exactly
    const float* src; bf16* dst; int k, n, N;
    if (id < WPN_)             { src = Wp; dst = wbuf;               k = id/96; n = id%96; N = 96; }
    else if (id < WPN_ + W1N_) { int t = id - WPN_;
                                 src = W1; dst = wbuf + WPN_;        k = t/384; n = t%384; N = 384; }
    else                       { int t = id - WPN_ - W1N_;
                                 src = W2; dst = wbuf + WPN_ + W1N_; k = t/96;  n = t%96;  N = 96; }
    int idx = ((k>>3)*(N>>4) + (n>>4))*128 + ((n&15)<<3) + (k&7);
    dst[idx] = __float2bfloat16(src[(size_t)k*N + n]);
  }

  // ---- stage head weights (shared) ----
  for (int idx = tid; idx < 48*48; idx += 256) {
    int c = idx / 48, dp = idx % 48;
    int mat = c >> 4, e = c & 15;
    const float* Wm = (mat == 0 ? Wk : (mat == 1 ? Wv : Wq)) + h*(D_*E_);
    wpl[c][dp] = packbf(Wm[(2*dp)*16 + e], Wm[(2*dp+1)*16 + e]);
  }
  __syncthreads();   // bar1: wpl staged (cross-wave RAW); hts untouched yet

  // ---- LN1 + QKV: 4 row-tiles of 64; hts/Ks/Vt wave-private -> fences only ----
  v4f qacc[4];
  {
    const int r  = lane >> 2;
    const int cg = lane & 3;
    float gv[24], bv[24];
    #pragma unroll
    for (int i = 0; i < 24; ++i) { gv[i] = g1[cg*24 + i]; bv[i] = bln1[cg*24 + i]; }

    for (int rt = 0; rt < 4; ++rt) {
      wfence();                        // prev tile's frag reads done (same-wave WAR)
      const int lrow = w*16 + r;
      const int row  = rt*64 + lrow;
      const float4* xp = (const float4*)(x + ((size_t)(b*256 + row)*96 + cg*24));
      float xv[24];
      #pragma unroll
      for (int p = 0; p < 6; ++p) {
        float4 t4 = xp[p];
        xv[4*p+0] = t4.x; xv[4*p+1] = t4.y; xv[4*p+2] = t4.z; xv[4*p+3] = t4.w;
      }
      float s1 = 0.f, s2 = 0.f;
      #pragma unroll
      for (int i = 0; i < 24; ++i) { s1 += xv[i]; s2 = fmaf(xv[i], xv[i], s2); }
      s1 += __shfl_xor(s1, 1); s2 += __shfl_xor(s2, 1);
      s1 += __shfl_xor(s1, 2); s2 += __shfl_xor(s2, 2);
      float mm = s1 * (1.0f/96.0f);
      float rs = rsqrtf(s2 * (1.0f/96.0f) - mm*mm + 1e-5f);
      #pragma unroll
      for (int p = 0; p < 12; ++p) {
        float h0 = (xv[2*p]   - mm)*rs*gv[2*p]   + bv[2*p];
        float h1 = (xv[2*p+1] - mm)*rs*gv[2*p+1] + bv[2*p+1];
        *(uint32_t*)&hts[lrow*104 + cg*24 + 2*p] = packbf(h0, h1);
      }
      wfence();                        // LN writes before frag reads (same-wave RAW)

      v8s ah[3];
      #pragma unroll
      for (int ks = 0; ks < 3; ++ks)
        ah[ks] = *(const v8s*)&hts[(w*16 + l15)*104 + ks*32 + quad*8];
      #pragma unroll
      for (int nt = 0; nt < 3; ++nt) {
        v4f acc = {0.f,0.f,0.f,0.f};
        #pragma unroll
        for (int ks = 0; ks < 3; ++ks) {
          v8s bb = *(const v8s*)&wpl[nt*16 + l15][ks*16 + quad*4];
          acc = __builtin_amdgcn_mfma_f32_16x16x32_bf16(ah[ks], bb, acc, 0, 0, 0);
        }
        int tr0 = rt*64 + w*16 + quad*4;
        if (nt == 0) {          // K
          #pragma unroll
          for (int r2 = 0; r2 < 4; ++r2) Ks[tr0 + r2][l15] = f2b(acc[r2]);
        } else if (nt == 1) {   // V -> V^T
          *(uint32_t*)&Vt[l15][tr0]     = packbf(acc[0], acc[1]);
          *(uint32_t*)&Vt[l15][tr0 + 2] = packbf(acc[2], acc[3]);
        } else {                // Q stays in regs
          qacc[rt] = acc;
        }
      }
    }
  }
  __syncthreads();   // bar2: Ks/Vt writes visible cross-wave (flash reads all rows)

  // ---- Q: C-layout regs -> B-frag regs via per-wave Pb (aliases hts) ----
  uint16_t* Pb = &hts[(w*16)*104];     // wave-private scratch, stride 40 (80B)
  v8s qf[4];
  v8s zero8;
  #pragma unroll
  for (int j = 0; j < 8; ++j) zero8[j] = 0;
  #pragma unroll
  for (int rt = 0; rt < 4; ++rt) {
    wfence();
    #pragma unroll
    for (int r2 = 0; r2 < 4; ++r2)
      Pb[(quad*4 + r2)*40 + l15] = f2b(qacc[rt][r2] * 0.25f);   // E^-0.5
    wfence();
    qf[rt] = (quad < 2) ? *(const v8s*)&Pb[l15*40 + quad*8] : zero8;
  }

  // ---- streaming flash, in-register P (swapped QK^T; no LDS, no fences) ----
  v4s ones4;
  #pragma unroll
  for (int j = 0; j < 4; ++j) ones4[j] = (short)0x3F80;

  v4f oacc[4], lac[4];
  #pragma unroll
  for (int i = 0; i < 4; ++i) { oacc[i] = (v4f){0.f,0.f,0.f,0.f}; lac[i] = (v4f){0.f,0.f,0.f,0.f}; }

  for (int sb = 0; sb < 8; ++sb) {
    v8s kf0 = (quad < 2) ? *(const v8s*)&Ks[sb*32      + l15][quad*8] : zero8;
    v8s kf1 = (quad < 2) ? *(const v8s*)&Ks[sb*32 + 16 + l15][quad*8] : zero8;
    v4s vb0 = *(const v4s*)&Vt[l15][sb*32      + quad*4];
    v4s vb1 = *(const v4s*)&Vt[l15][sb*32 + 16 + quad*4];
    const int sbase = sb*32 + quad*4;
    #pragma unroll
    for (int i = 0; i < 4; ++i) {
      int mt = 4*i + w;
      if (mt >= 2*sb) {
        v4f z = {0.f,0.f,0.f,0.f};
        v4f s0t = __builtin_amdgcn_mfma_f32_16x16x32_bf16(kf0, qf[i], z, 0, 0, 0);
        v4f s1t = __builtin_amdgcn_mfma_f32_16x16x32_bf16(kf1, qf[i], z, 0, 0, 0);
        const int qg = mt*16 + l15;
        float p00 = (sbase + 0      > qg) ? 0.f : __expf(s0t[0]);
        float p01 = (sbase + 1      > qg) ? 0.f : __expf(s0t[1]);
        float p02 = (sbase + 2      > qg) ? 0.f : __expf(s0t[2]);
        float p03 = (sbase + 3      > qg) ? 0.f : __expf(s0t[3]);
        float p10 = (sbase + 16     > qg) ? 0.f : __expf(s1t[0]);
        float p11 = (sbase + 17     > qg) ? 0.f : __expf(s1t[1]);
        float p12 = (sbase + 18     > qg) ? 0.f : __expf(s1t[2]);
        float p13 = (sbase + 19     > qg) ? 0.f : __expf(s1t[3]);
        v4s pa0 = pack4(p00, p01, p02, p03);
        v4s pa1 = pack4(p10, p11, p12, p13);
        oacc[i] = mfma16(pa0, vb0,   oacc[i]);
        oacc[i] = mfma16(pa1, vb1,   oacc[i]);
        lac[i]  = mfma16(pa0, ones4, lac[i]);
        lac[i]  = mfma16(pa1, ones4, lac[i]);
      }
    }
  }

  #pragma unroll
  for (int i = 0; i < 4; ++i) {
    int mt = 4*i + w;
    #pragma unroll
    for (int r2 = 0; r2 < 4; ++r2) {
      float inv = 1.0f / lac[i][r2];
      size_t idx = ((size_t)b*256 + mt*16 + quad*4 + r2)*96 + h*16 + l15;
      o_ws[idx] = __float2bfloat16(oacc[i][r2] * inv);
    }
  }
}

// =================== K_B: wave-split MFMA proj/FF (7 blocks/CU, no-spill) ===
// Block = 32 rows, 4 waves: wp = w>>1 (row-half), s = w&1 (col-side).
// r26 = r23 structure (dbuf FF overlap, ffp bf16 residual, inline noise2)
// at launch_bounds(256,7): ~72-reg budget (~56V+16A) fits FF's ~55-reg peak.
__global__ __launch_bounds__(256, 7)
void k_proj_ff(const float* __restrict__ x, const bf16* __restrict__ o_ws,
               const bf16* __restrict__ wb,
               const float* __restrict__ bp,
               const float* __restrict__ g2, const float* __restrict__ bln2,
               const float* __restrict__ b1, const float* __restrict__ b2,
               float* __restrict__ out,
               uint32_t n1k0, uint32_t n1k1, uint32_t n2k0, uint32_t n2k1)
{
  __shared__ __align__(16) uint16_t t2[2][32][104];  // dbuf: h2 (buf0), then f1 chunks
  __shared__ __align__(8)  float2  st[32][2];        // LN2 partial stats per (row, side)

  const bf16* wpb = wb;
  const bf16* w1b = wb + WPN_;
  const bf16* w2b = wb + WPN_ + W1N_;

  const int tid  = threadIdx.x;
  const int w    = tid >> 6;
  const int wp   = w >> 1;          // row-half: rows wp*16 .. wp*16+15
  const int s    = w & 1;           // col-side: cols s*48 .. s*48+47
  const int lane = tid & 63;
  const int quad = lane >> 4;
  const int l15  = lane & 15;
  const int rowbase = blockIdx.x * 32;
  const uint32_t jbase = (uint32_t)rowbase * 96u;
  const int rloc = wp*16 + quad*4;  // first of this thread's 4 local rows

  #define BFRAG(Wb, Ndiv16, nt, k8) \
    (*(const v8s*)((Wb) + (((k8)*(Ndiv16) + (nt))*128 + l15*8)))

  uint32_t ffp[6];   // packed bf16 residual, set after LN2; [nt3*2 + (r>>1)]
  {
    // ---- phase 1: out-proj (3 nt of side s) + bias + residual + noise1 ----
    float ff[12];    // C-layout: ff[nt3*4+r]; dies at end of this scope
    {
      v8s ao[3];
      #pragma unroll
      for (int ks = 0; ks < 3; ++ks)
        ao[ks] = *(const v8s*)(o_ws + (size_t)(rowbase + wp*16 + l15)*96 + ks*32 + quad*8);
      #pragma unroll
      for (int nt3 = 0; nt3 < 3; ++nt3) {
        int nt = s*3 + nt3;
        int col = nt*16 + l15;
        v4f acc = {0.f,0.f,0.f,0.f};
        #pragma unroll
        for (int ks = 0; ks < 3; ++ks)
          acc = __builtin_amdgcn_mfma_f32_16x16x32_bf16(ao[ks], BFRAG(wpb, 6, nt, ks*4+quad), acc, 0, 0, 0);
        float bpv = bp[col];
        #pragma unroll
        for (int r = 0; r < 4; ++r) {
          int row = rloc + r;
          uint32_t j = jbase + (uint32_t)row*96u + (uint32_t)col;
          ff[nt3*4+r] = acc[r] + bpv + x[j] + 0.1f * jax_normal(n1k0, n1k1, j);
        }
      }
    }

    // ---- phase 2: LN2 (quad-tree partial + cross-side combine via st) ----
    float s1p[4], s2p[4];
    #pragma unroll
    for (int r = 0; r < 4; ++r) {
      float s1 = 0.f, s2 = 0.f;
      #pragma unroll
      for (int nt3 = 0; nt3 < 3; ++nt3) { float v = ff[nt3*4+r]; s1 += v; s2 = fmaf(v, v, s2); }
      s1 += __shfl_xor(s1, 1); s2 += __shfl_xor(s2, 1);
      s1 += __shfl_xor(s1, 2); s2 += __shfl_xor(s2, 2);
      s1 += __shfl_xor(s1, 4); s2 += __shfl_xor(s2, 4);
      s1 += __shfl_xor(s1, 8); s2 += __shfl_xor(s2, 8);
      s1p[r] = s1; s2p[r] = s2;
    }
    if (l15 == 0) {
      #pragma unroll
      for (int r = 0; r < 4; ++r) st[rloc + r][s] = make_float2(s1p[r], s2p[r]);
    }
    __syncthreads();   // bar1: both sides' partials visible

    float g2v[3], b2l[3];
    #pragma unroll
    for (int nt3 = 0; nt3 < 3; ++nt3) {
      g2v[nt3] = g2[s*48 + nt3*16 + l15];
      b2l[nt3] = bln2[s*48 + nt3*16 + l15];
    }
    #pragma unroll
    for (int r = 0; r < 4; ++r) {
      float2 pa = st[rloc + r][0], pb = st[rloc + r][1];
      float s1 = pa.x + pb.x, s2 = pa.y + pb.y;
      float mm = s1 * (1.0f/96.0f);
      float rs = rsqrtf(s2 * (1.0f/96.0f) - mm*mm + 1e-5f);
      #pragma unroll
      for (int nt3 = 0; nt3 < 3; ++nt3)
        t2[0][rloc + r][s*48 + nt3*16 + l15] =
            f2b((ff[nt3*4+r] - mm) * rs * g2v[nt3] + b2l[nt3]);
    }

    // ---- pack residual to bf16; ff dies here (register diet for FF) ----
    #pragma unroll
    for (int nt3 = 0; nt3 < 3; ++nt3) {
      ffp[nt3*2]   = packbf(ff[nt3*4+0], ff[nt3*4+1]);
      ffp[nt3*2+1] = packbf(ff[nt3*4+2], ff[nt3*4+3]);
    }
  }
  __syncthreads();   // bar2: full h2 rows assembled

  // ---- phase 3: FF. Side s: FF1 cols s*48.. of each chunk; FF2 output
  //      cols s*48.. over all 4 chunks (acc2 wave-private). ----
  v8s ah[3];
  #pragma unroll
  for (int ks = 0; ks < 3; ++ks)
    ah[ks] = *(const v8s*)&t2[0][wp*16 + l15][ks*32 + quad*8];
  v4f acc2[3];
  #pragma unroll
  for (int nt3 = 0; nt3 < 3; ++nt3) acc2[nt3] = (v4f){0.f,0.f,0.f,0.f};

  #define FF1C(C, DST) { \
    _Pragma("unroll") \
    for (int nt3 = 0; nt3 < 3; ++nt3) { \
      v4f a = {0.f,0.f,0.f,0.f}; \
      _Pragma("unroll") \
      for (int ks = 0; ks < 3; ++ks) \
        a = __builtin_amdgcn_mfma_f32_16x16x32_bf16(ah[ks], BFRAG(w1b, 24, (C)*6 + s*3 + nt3, ks*4+quad), a, 0, 0, 0); \
      float b1v = b1[(C)*96 + s*48 + nt3*16 + l15]; \
      _Pragma("unroll") \
      for (int r = 0; r < 4; ++r) \
        DST[rloc + r][s*48 + nt3*16 + l15] = f2b(fmaxf(a[r] + b1v, 0.f)); \
    } }

  #define FF2C(C, SRC) { \
    v8s af[3]; \
    _Pragma("unroll") \
    for (int ks = 0; ks < 3; ++ks) \
      af[ks] = *(const v8s*)&SRC[wp*16 + l15][ks*32 + quad*8]; \
    _Pragma("unroll") \
    for (int nt3 = 0; nt3 < 3; ++nt3) { \
      _Pragma("unroll") \
      for (int ks = 0; ks < 3; ++ks) \
        acc2[nt3] = __builtin_amdgcn_mfma_f32_16x16x32_bf16(af[ks], BFRAG(w2b, 6, s*3 + nt3, ((C)*3+ks)*4+quad), acc2[nt3], 0, 0, 0); \
    } }

  FF1C(0, t2[1])
  __syncthreads();   // bar3: ah reads done (t2[0] reusable) + f1(0) visible
  FF1C(1, t2[0])
  FF2C(0, t2[1])
  __syncthreads();   // bar4: f1(1) visible; f1(0) reads done before overwrite
  FF1C(2, t2[1])
  FF2C(1, t2[0])
  __syncthreads();   // bar5
  FF1C(3, t2[0])
  FF2C(2, t2[1])
  __syncthreads();   // bar6
  FF2C(3, t2[0])

  // ---- epilogue: out = x1(bf16) + C + b2 + 0.1*noise2 (inline) ----
  #pragma unroll
  for (int nt3 = 0; nt3 < 3; ++nt3) {
    int col = s*48 + nt3*16 + l15;
    float b2v = b2[col];
    #pragma unroll
    for (int r = 0; r < 4; ++r) {
      int row = rloc + r;
      uint32_t j = jbase + (uint32_t)row*96u + (uint32_t)col;
      uint32_t pk = ffp[nt3*2 + (r>>1)];
      float x1v = (r&1) ? bhi(pk) : blo(pk);
      out[(size_t)(rowbase + row)*96 + col] =
          x1v + acc2[nt3][r] + b2v + 0.1f * jax_normal(n2k0, n2k1, j);
    }
  }
  #undef FF2C
  #undef FF1C
  #undef BFRAG
}

// diagnostic fallback: ws too small -> zero out (absmax signature 5.125)
__global__ __launch_bounds__(256)
void k_zero(float* __restrict__ out)
{
  int i = blockIdx.x*256 + threadIdx.x;
  if (i < NTOK_) out[i] = 0.0f;
}

extern "C" void kernel_launch(void* const* d_in, const int* in_sizes, int n_in,
                              void* d_out, int out_size, void* d_ws, size_t ws_size,
                              hipStream_t stream) {
  const float* x    = (const float*)d_in[0];
  const float* Wq   = (const float*)d_in[1];
  const float* Wk   = (const float*)d_in[2];
  const float* Wv   = (const float*)d_in[3];
  const float* Wp   = (const float*)d_in[4];
  const float* bp   = (const float*)d_in[5];
  const float* g1   = (const float*)d_in[6];
  const float* bln1 = (const float*)d_in[7];
  const float* g2   = (const float*)d_in[8];
  const float* bln2 = (const float*)d_in[9];
  const float* W1   = (const float*)d_in[10];
  const float* b1   = (const float*)d_in[11];
  const float* W2   = (const float*)d_in[12];
  const float* b2   = (const float*)d_in[13];
  float* out = (float*)d_out;

  size_t need = (size_t)NTOK_*sizeof(bf16) + (size_t)WTOT_*sizeof(bf16);
  if (ws_size < need) {
    hipLaunchKernelGGL(k_zero, dim3((NTOK_ + 255)/256), dim3(256), 0, stream, out);
    return;
  }
  bf16* o_ws = (bf16*)d_ws;
  bf16* wbuf = o_ws + NTOK_;

  uint32_t n1k0 = 0u, n1k1 = 0u; tf2x32(0u, 42u, n1k0, n1k1);
  uint32_t n2k0 = 0u, n2k1 = 1u; tf2x32(0u, 42u, n2k0, n2k1);

  hipLaunchKernelGGL(k_attn_fused, dim3(B_*H_), dim3(256), 0, stream,
                     x, Wq, Wk, Wv, g1, bln1, o_ws, Wp, W1, W2, wbuf);
  hipLaunchKernelGGL(k_proj_ff, dim3(BT_/32), dim3(256), 0, stream,
                     x, o_ws, wbuf, bp, g2, bln2, b1, b2, out,
                     n1k0, n1k1, n2k0, n2k1);
}

// Round 16
// 190.546 us; speedup vs baseline: 1.0255x; 1.0255x over previous
//
#include <hip/hip_runtime.h>
#include <hip/hip_bf16.h>
#include <stdint.h>

// Decoder block B=256,T=256,D=96,H=6,E=16,DFF=384. f32 in/out, f32 acc.
// Round 27 = FINAL: revert to r23, the best-measured configuration
// (total 191.2us; session start 209.3). k_attn = r22 (in-register-P flash
// via swapped QK^T + K=16 PV MFMAs, 2 barriers, 4 blocks/CU). k_proj_ff =
// r23 (wave-split, dbuf FF overlap, bf16-packed residual, inline noise2,
// (256,8) = 8 blocks/CU). r23 carries ~43MB known scratch spill but the
// occupancy it buys (45->66%) outweighs it; r24/r25/r26 mapped the
// spill-vs-occupancy frontier and all regressed:
//   (256,6) no-spill 62.0us | (256,8) diet 60.0us | (256,8) v2 63.7
//   (256,8) L2-park 65.1    | (256,7) 64.0
// Noise: jax threefry2x32 PARTITIONABLE scheme (verified round 5).

#define B_    256
#define T_    256
#define D_    96
#define H_    6
#define E_    16
#define DFF_  384
#define BT_   (B_*T_)        // 65536
#define NTOK_ (BT_*D_)       // 6291456
#define WPN_  (96*96)        // 9216
#define W1N_  (96*384)       // 36864
#define W2N_  (384*96)       // 36864
#define WTOT_ (WPN_+W1N_+W2N_)  // 82944 elems

typedef __hip_bfloat16 bf16;
typedef __attribute__((ext_vector_type(8))) short v8s;
typedef __attribute__((ext_vector_type(4))) short v4s;
typedef __attribute__((ext_vector_type(4))) float v4f;

// compiler-only memory fence: stops reordering of LDS ops across it.
// HW executes DS ops of a wave in order, so this suffices for wave-private
// cross-lane LDS communication (no s_barrier cost).
__device__ __forceinline__ void wfence(){ __asm__ volatile("" ::: "memory"); }

__host__ __device__ inline uint32_t rotl32(uint32_t x, int r){ return (x<<r)|(x>>(32-r)); }

__host__ __device__ inline void tf2x32(uint32_t k0, uint32_t k1, uint32_t& x0, uint32_t& x1){
  uint32_t ks2 = k0 ^ k1 ^ 0x1BD11BDAu;
  x0 += k0; x1 += k1;
#define TF_R(r) { x0 += x1; x1 = rotl32(x1, r); x1 ^= x0; }
  TF_R(13) TF_R(15) TF_R(26) TF_R(6)
  x0 += k1;  x1 += ks2 + 1u;
  TF_R(17) TF_R(29) TF_R(16) TF_R(24)
  x0 += ks2; x1 += k0 + 2u;
  TF_R(13) TF_R(15) TF_R(26) TF_R(6)
  x0 += k0;  x1 += k1 + 3u;
  TF_R(17) TF_R(29) TF_R(16) TF_R(24)
  x0 += k1;  x1 += ks2 + 4u;
  TF_R(13) TF_R(15) TF_R(26) TF_R(6)
  x0 += ks2; x1 += k0 + 5u;
#undef TF_R
}

// XLA f32 ErfInv, fast log path: -log1p(-x^2) == -ln2*log2((1-x)(1+x))
__device__ __forceinline__ float erfinv32(float x){
  float w = -0.69314718056f * __log2f((1.0f - x) * (1.0f + x));
  float p;
  if (w < 5.0f) {
    w -= 2.5f;
    p = 2.81022636e-08f;
    p = fmaf(p, w, 3.43273939e-07f);
    p = fmaf(p, w, -3.5233877e-06f);
    p = fmaf(p, w, -4.39150654e-06f);
    p = fmaf(p, w, 0.00021858087f);
    p = fmaf(p, w, -0.00125372503f);
    p = fmaf(p, w, -0.00417768164f);
    p = fmaf(p, w, 0.246640727f);
    p = fmaf(p, w, 1.50140941f);
  } else {
    w = sqrtf(w) - 3.0f;
    p = -0.000200214257f;
    p = fmaf(p, w, 0.000100950558f);
    p = fmaf(p, w, 0.00134934322f);
    p = fmaf(p, w, -0.00367342844f);
    p = fmaf(p, w, 0.00573950773f);
    p = fmaf(p, w, -0.0076224613f);
    p = fmaf(p, w, 0.00943887047f);
    p = fmaf(p, w, 1.00167406f);
    p = fmaf(p, w, 2.83297682f);
  }
  return p * x;
}

__device__ __forceinline__ float jax_normal(uint32_t k0, uint32_t k1, uint32_t j){
  uint32_t x0 = 0u, x1 = j;
  tf2x32(k0, k1, x0, x1);
  uint32_t bits = x0 ^ x1;
  float f = __uint_as_float((bits >> 9) | 0x3F800000u) - 1.0f;
  const float lo = -0.99999994f;
  float u = fmaxf(lo, fmaf(f, 2.0f, lo));
  return 1.41421356f * erfinv32(u);
}

__device__ __forceinline__ float blo(uint32_t u){ return __uint_as_float(u << 16); }
__device__ __forceinline__ float bhi(uint32_t u){ return __uint_as_float(u & 0xFFFF0000u); }
__device__ __forceinline__ uint16_t f2b(float f){
  union { bf16 h; uint16_t u; } x; x.h = __float2bfloat16(f); return x.u;
}
__device__ __forceinline__ uint32_t packbf(float a, float b){
  return (uint32_t)f2b(a) | ((uint32_t)f2b(b) << 16);
}
__device__ __forceinline__ v4s pack4(float a, float b, float c, float d){
  uint64_t both = ((uint64_t)packbf(c, d) << 32) | (uint64_t)packbf(a, b);
  v4s r; __builtin_memcpy(&r, &both, 8); return r;
}

// K=16 bf16 MFMA (v_mfma_f32_16x16x16_bf16): builtin name varies by ROCm.
__device__ __forceinline__ v4f mfma16(v4s a, v4s b, v4f c){
#if __has_builtin(__builtin_amdgcn_mfma_f32_16x16x16_bf16)
  return __builtin_amdgcn_mfma_f32_16x16x16_bf16(a, b, c, 0, 0, 0);
#elif __has_builtin(__builtin_amdgcn_mfma_f32_16x16x16bf16_1k)
  return __builtin_amdgcn_mfma_f32_16x16x16bf16_1k(a, b, c, 0, 0, 0);
#else
  v4f d;
  asm volatile("v_mfma_f32_16x16x16_bf16 %0, %1, %2, %3"
               : "=v"(d) : "v"(a), "v"(b), "v"(c));
  return d;
#endif
}

// =================== K_A: prep-fold + LN1 + MFMA QKV + MFMA flash ===========
__global__ __launch_bounds__(256, 4)
void k_attn_fused(const float* __restrict__ x,
                  const float* __restrict__ Wq, const float* __restrict__ Wk,
                  const float* __restrict__ Wv,
                  const float* __restrict__ g1, const float* __restrict__ bln1,
                  bf16* __restrict__ o_ws,
                  const float* __restrict__ Wp, const float* __restrict__ W1,
                  const float* __restrict__ W2, bf16* __restrict__ wbuf)
{
  __shared__ __align__(16) uint16_t hts[64*104];   // LN tile; Pb aliases (wave-private rows)
  __shared__ __align__(16) uint32_t wpl[48][52];   // head W pairs (RO after stage)
  __shared__ __align__(16) uint16_t Ks[256][16];   // k rows, 16 e-cols, 32B stride
  __shared__ __align__(16) uint16_t Vt[16][264];   // V^T[e][s]

  const int tid  = threadIdx.x;
  const int bh   = blockIdx.x;
  const int b    = bh / H_, h = bh % H_;
  const int w    = tid >> 6;
  const int lane = tid & 63;
  const int quad = lane >> 4;
  const int l15  = lane & 15;

  // ---- folded k_prep: 54 weight elems per block -> wbuf fragment-major ----
  if (tid < 54) {
    int id = bh*54 + tid;   // < 82944 exactly
    const float* src; bf16* dst; int k, n, N;
    if (id < WPN_)             { src = Wp; dst = wbuf;               k = id/96; n = id%96; N = 96; }
    else if (id < WPN_ + W1N_) { int t = id - WPN_;
                                 src = W1; dst = wbuf + WPN_;        k = t/384; n = t%384; N = 384; }
    else                       { int t = id - WPN_ - W1N_;
                                 src = W2; dst = wbuf + WPN_ + W1N_; k = t/96;  n = t%96;  N = 96; }
    int idx = ((k>>3)*(N>>4) + (n>>4))*128 + ((n&15)<<3) + (k&7);
    dst[idx] = __float2bfloat16(src[(size_t)k*N + n]);
  }

  // ---- stage head weights (shared) ----
  for (int idx = tid; idx < 48*48; idx += 256) {
    int c = idx / 48, dp = idx % 48;
    int mat = c >> 4, e = c & 15;
    const float* Wm = (mat == 0 ? Wk : (mat == 1 ? Wv : Wq)) + h*(D_*E_);
    wpl[c][dp] = packbf(Wm[(2*dp)*16 + e], Wm[(2*dp+1)*16 + e]);
  }
  __syncthreads();   // bar1: wpl staged (cross-wave RAW); hts untouched yet

  // ---- LN1 + QKV: 4 row-tiles of 64; hts/Ks/Vt wave-private -> fences only ----
  v4f qacc[4];
  {
    const int r  = lane >> 2;
    const int cg = lane & 3;
    float gv[24], bv[24];
    #pragma unroll
    for (int i = 0; i < 24; ++i) { gv[i] = g1[cg*24 + i]; bv[i] = bln1[cg*24 + i]; }

    for (int rt = 0; rt < 4; ++rt) {
      wfence();                        // prev tile's frag reads done (same-wave WAR)
      const int lrow = w*16 + r;
      const int row  = rt*64 + lrow;
      const float4* xp = (const float4*)(x + ((size_t)(b*256 + row)*96 + cg*24));
      float xv[24];
      #pragma unroll
      for (int p = 0; p < 6; ++p) {
        float4 t4 = xp[p];
        xv[4*p+0] = t4.x; xv[4*p+1] = t4.y; xv[4*p+2] = t4.z; xv[4*p+3] = t4.w;
      }
      float s1 = 0.f, s2 = 0.f;
      #pragma unroll
      for (int i = 0; i < 24; ++i) { s1 += xv[i]; s2 = fmaf(xv[i], xv[i], s2); }
      s1 += __shfl_xor(s1, 1); s2 += __shfl_xor(s2, 1);
      s1 += __shfl_xor(s1, 2); s2 += __shfl_xor(s2, 2);
      float mm = s1 * (1.0f/96.0f);
      float rs = rsqrtf(s2 * (1.0f/96.0f) - mm*mm + 1e-5f);
      #pragma unroll
      for (int p = 0; p < 12; ++p) {
        float h0 = (xv[2*p]   - mm)*rs*gv[2*p]   + bv[2*p];
        float h1 = (xv[2*p+1] - mm)*rs*gv[2*p+1] + bv[2*p+1];
        *(uint32_t*)&hts[lrow*104 + cg*24 + 2*p] = packbf(h0, h1);
      }
      wfence();                        // LN writes before frag reads (same-wave RAW)

      v8s ah[3];
      #pragma unroll
      for (int ks = 0; ks < 3; ++ks)
        ah[ks] = *(const v8s*)&hts[(w*16 + l15)*104 + ks*32 + quad*8];
      #pragma unroll
      for (int nt = 0; nt < 3; ++nt) {
        v4f acc = {0.f,0.f,0.f,0.f};
        #pragma unroll
        for (int ks = 0; ks < 3; ++ks) {
          v8s bb = *(const v8s*)&wpl[nt*16 + l15][ks*16 + quad*4];
          acc = __builtin_amdgcn_mfma_f32_16x16x32_bf16(ah[ks], bb, acc, 0, 0, 0);
        }
        int tr0 = rt*64 + w*16 + quad*4;
        if (nt == 0) {          // K
          #pragma unroll
          for (int r2 = 0; r2 < 4; ++r2) Ks[tr0 + r2][l15] = f2b(acc[r2]);
        } else if (nt == 1) {   // V -> V^T
          *(uint32_t*)&Vt[l15][tr0]     = packbf(acc[0], acc[1]);
          *(uint32_t*)&Vt[l15][tr0 + 2] = packbf(acc[2], acc[3]);
        } else {                // Q stays in regs
          qacc[rt] = acc;
        }
      }
    }
  }
  __syncthreads();   // bar2: Ks/Vt writes visible cross-wave (flash reads all rows)

  // ---- Q: C-layout regs -> B-frag regs via per-wave Pb (aliases hts) ----
  uint16_t* Pb = &hts[(w*16)*104];     // wave-private scratch, stride 40 (80B)
  v8s qf[4];
  v8s zero8;
  #pragma unroll
  for (int j = 0; j < 8; ++j) zero8[j] = 0;
  #pragma unroll
  for (int rt = 0; rt < 4; ++rt) {
    wfence();
    #pragma unroll
    for (int r2 = 0; r2 < 4; ++r2)
      Pb[(quad*4 + r2)*40 + l15] = f2b(qacc[rt][r2] * 0.25f);   // E^-0.5
    wfence();
    qf[rt] = (quad < 2) ? *(const v8s*)&Pb[l15*40 + quad*8] : zero8;
  }

  // ---- streaming flash, in-register P (swapped QK^T; no LDS, no fences) ----
  v4s ones4;
  #pragma unroll
  for (int j = 0; j < 4; ++j) ones4[j] = (short)0x3F80;

  v4f oacc[4], lac[4];
  #pragma unroll
  for (int i = 0; i < 4; ++i) { oacc[i] = (v4f){0.f,0.f,0.f,0.f}; lac[i] = (v4f){0.f,0.f,0.f,0.f}; }

  for (int sb = 0; sb < 8; ++sb) {
    v8s kf0 = (quad < 2) ? *(const v8s*)&Ks[sb*32      + l15][quad*8] : zero8;
    v8s kf1 = (quad < 2) ? *(const v8s*)&Ks[sb*32 + 16 + l15][quad*8] : zero8;
    v4s vb0 = *(const v4s*)&Vt[l15][sb*32      + quad*4];
    v4s vb1 = *(const v4s*)&Vt[l15][sb*32 + 16 + quad*4];
    const int sbase = sb*32 + quad*4;
    #pragma unroll
    for (int i = 0; i < 4; ++i) {
      int mt = 4*i + w;
      if (mt >= 2*sb) {
        v4f z = {0.f,0.f,0.f,0.f};
        v4f s0t = __builtin_amdgcn_mfma_f32_16x16x32_bf16(kf0, qf[i], z, 0, 0, 0);
        v4f s1t = __builtin_amdgcn_mfma_f32_16x16x32_bf16(kf1, qf[i], z, 0, 0, 0);
        const int qg = mt*16 + l15;
        float p00 = (sbase + 0      > qg) ? 0.f : __expf(s0t[0]);
        float p01 = (sbase + 1      > qg) ? 0.f : __expf(s0t[1]);
        float p02 = (sbase + 2      > qg) ? 0.f : __expf(s0t[2]);
        float p03 = (sbase + 3      > qg) ? 0.f : __expf(s0t[3]);
        float p10 = (sbase + 16     > qg) ? 0.f : __expf(s1t[0]);
        float p11 = (sbase + 17     > qg) ? 0.f : __expf(s1t[1]);
        float p12 = (sbase + 18     > qg) ? 0.f : __expf(s1t[2]);
        float p13 = (sbase + 19     > qg) ? 0.f : __expf(s1t[3]);
        v4s pa0 = pack4(p00, p01, p02, p03);
        v4s pa1 = pack4(p10, p11, p12, p13);
        oacc[i] = mfma16(pa0, vb0,   oacc[i]);
        oacc[i] = mfma16(pa1, vb1,   oacc[i]);
        lac[i]  = mfma16(pa0, ones4, lac[i]);
        lac[i]  = mfma16(pa1, ones4, lac[i]);
      }
    }
  }

  #pragma unroll
  for (int i = 0; i < 4; ++i) {
    int mt = 4*i + w;
    #pragma unroll
    for (int r2 = 0; r2 < 4; ++r2) {
      float inv = 1.0f / lac[i][r2];
      size_t idx = ((size_t)b*256 + mt*16 + quad*4 + r2)*96 + h*16 + l15;
      o_ws[idx] = __float2bfloat16(oacc[i][r2] * inv);
    }
  }
}

// =================== K_B: wave-split MFMA proj/FF (8 blocks/CU) =============
// Block = 32 rows, 4 waves: wp = w>>1 (row-half), s = w&1 (col-side).
// r23 diet: residual packed bf16 ffp[6] after LN2 (ff dies pre-FF), noise2
// inline in epilogue. launch_bounds(256,8): grid 2048 = exactly 8 resident
// blocks/CU -> single round, no tail. Carries known ~43MB scratch spill;
// measured optimum of the spill-vs-occupancy frontier (see header table).
__global__ __launch_bounds__(256, 8)
void k_proj_ff(const float* __restrict__ x, const bf16* __restrict__ o_ws,
               const bf16* __restrict__ wb,
               const float* __restrict__ bp,
               const float* __restrict__ g2, const float* __restrict__ bln2,
               const float* __restrict__ b1, const float* __restrict__ b2,
               float* __restrict__ out,
               uint32_t n1k0, uint32_t n1k1, uint32_t n2k0, uint32_t n2k1)
{
  __shared__ __align__(16) uint16_t t2[2][32][104];  // dbuf: h2 (buf0), then f1 chunks
  __shared__ __align__(8)  float2  st[32][2];        // LN2 partial stats per (row, side)

  const bf16* wpb = wb;
  const bf16* w1b = wb + WPN_;
  const bf16* w2b = wb + WPN_ + W1N_;

  const int tid  = threadIdx.x;
  const int w    = tid >> 6;
  const int wp   = w >> 1;          // row-half: rows wp*16 .. wp*16+15
  const int s    = w & 1;           // col-side: cols s*48 .. s*48+47
  const int lane = tid & 63;
  const int quad = lane >> 4;
  const int l15  = lane & 15;
  const int rowbase = blockIdx.x * 32;
  const uint32_t jbase = (uint32_t)rowbase * 96u;
  const int rloc = wp*16 + quad*4;  // first of this thread's 4 local rows

  #define BFRAG(Wb, Ndiv16, nt, k8) \
    (*(const v8s*)((Wb) + (((k8)*(Ndiv16) + (nt))*128 + l15*8)))

  uint32_t ffp[6];   // packed bf16 residual, set after LN2; [nt3*2 + (r>>1)]
  {
    // ---- phase 1: out-proj (3 nt of side s) + bias + residual + noise1 ----
    float ff[12];    // C-layout: ff[nt3*4+r]; dies at end of this scope
    {
      v8s ao[3];
      #pragma unroll
      for (int ks = 0; ks < 3; ++ks)
        ao[ks] = *(const v8s*)(o_ws + (size_t)(rowbase + wp*16 + l15)*96 + ks*32 + quad*8);
      #pragma unroll
      for (int nt3 = 0; nt3 < 3; ++nt3) {
        int nt = s*3 + nt3;
        int col = nt*16 + l15;
        v4f acc = {0.f,0.f,0.f,0.f};
        #pragma unroll
        for (int ks = 0; ks < 3; ++ks)
          acc = __builtin_amdgcn_mfma_f32_16x16x32_bf16(ao[ks], BFRAG(wpb, 6, nt, ks*4+quad), acc, 0, 0, 0);
        float bpv = bp[col];
        #pragma unroll
        for (int r = 0; r < 4; ++r) {
          int row = rloc + r;
          uint32_t j = jbase + (uint32_t)row*96u + (uint32_t)col;
          ff[nt3*4+r] = acc[r] + bpv + x[j] + 0.1f * jax_normal(n1k0, n1k1, j);
        }
      }
    }

    // ---- phase 2: LN2 (quad-tree partial + cross-side combine via st) ----
    float s1p[4], s2p[4];
    #pragma unroll
    for (int r = 0; r < 4; ++r) {
      float s1 = 0.f, s2 = 0.f;
      #pragma unroll
      for (int nt3 = 0; nt3 < 3; ++nt3) { float v = ff[nt3*4+r]; s1 += v; s2 = fmaf(v, v, s2); }
      s1 += __shfl_xor(s1, 1); s2 += __shfl_xor(s2, 1);
      s1 += __shfl_xor(s1, 2); s2 += __shfl_xor(s2, 2);
      s1 += __shfl_xor(s1, 4); s2 += __shfl_xor(s2, 4);
      s1 += __shfl_xor(s1, 8); s2 += __shfl_xor(s2, 8);
      s1p[r] = s1; s2p[r] = s2;
    }
    if (l15 == 0) {
      #pragma unroll
      for (int r = 0; r < 4; ++r) st[rloc + r][s] = make_float2(s1p[r], s2p[r]);
    }
    __syncthreads();   // bar1: both sides' partials visible

    float g2v[3], b2l[3];
    #pragma unroll
    for (int nt3 = 0; nt3 < 3; ++nt3) {
      g2v[nt3] = g2[s*48 + nt3*16 + l15];
      b2l[nt3] = bln2[s*48 + nt3*16 + l15];
    }
    #pragma unroll
    for (int r = 0; r < 4; ++r) {
      float2 pa = st[rloc + r][0], pb = st[rloc + r][1];
      float s1 = pa.x + pb.x, s2 = pa.y + pb.y;
      float mm = s1 * (1.0f/96.0f);
      float rs = rsqrtf(s2 * (1.0f/96.0f) - mm*mm + 1e-5f);
      #pragma unroll
      for (int nt3 = 0; nt3 < 3; ++nt3)
        t2[0][rloc + r][s*48 + nt3*16 + l15] =
            f2b((ff[nt3*4+r] - mm) * rs * g2v[nt3] + b2l[nt3]);
    }

    // ---- pack residual to bf16; ff dies here (register diet for FF) ----
    #pragma unroll
    for (int nt3 = 0; nt3 < 3; ++nt3) {
      ffp[nt3*2]   = packbf(ff[nt3*4+0], ff[nt3*4+1]);
      ffp[nt3*2+1] = packbf(ff[nt3*4+2], ff[nt3*4+3]);
    }
  }
  __syncthreads();   // bar2: full h2 rows assembled

  // ---- phase 3: FF. Side s: FF1 cols s*48.. of each chunk; FF2 output
  //      cols s*48.. over all 4 chunks (acc2 wave-private). ----
  v8s ah[3];
  #pragma unroll
  for (int ks = 0; ks < 3; ++ks)
    ah[ks] = *(const v8s*)&t2[0][wp*16 + l15][ks*32 + quad*8];
  v4f acc2[3];
  #pragma unroll
  for (int nt3 = 0; nt3 < 3; ++nt3) acc2[nt3] = (v4f){0.f,0.f,0.f,0.f};

  #define FF1C(C, DST) { \
    _Pragma("unroll") \
    for (int nt3 = 0; nt3 < 3; ++nt3) { \
      v4f a = {0.f,0.f,0.f,0.f}; \
      _Pragma("unroll") \
      for (int ks = 0; ks < 3; ++ks) \
        a = __builtin_amdgcn_mfma_f32_16x16x32_bf16(ah[ks], BFRAG(w1b, 24, (C)*6 + s*3 + nt3, ks*4+quad), a, 0, 0, 0); \
      float b1v = b1[(C)*96 + s*48 + nt3*16 + l15]; \
      _Pragma("unroll") \
      for (int r = 0; r < 4; ++r) \
        DST[rloc + r][s*48 + nt3*16 + l15] = f2b(fmaxf(a[r] + b1v, 0.f)); \
    } }

  #define FF2C(C, SRC) { \
    v8s af[3]; \
    _Pragma("unroll") \
    for (int ks = 0; ks < 3; ++ks) \
      af[ks] = *(const v8s*)&SRC[wp*16 + l15][ks*32 + quad*8]; \
    _Pragma("unroll") \
    for (int nt3 = 0; nt3 < 3; ++nt3) { \
      _Pragma("unroll") \
      for (int ks = 0; ks < 3; ++ks) \
        acc2[nt3] = __builtin_amdgcn_mfma_f32_16x16x32_bf16(af[ks], BFRAG(w2b, 6, s*3 + nt3, ((C)*3+ks)*4+quad), acc2[nt3], 0, 0, 0); \
    } }

  FF1C(0, t2[1])
  __syncthreads();   // bar3: ah reads done (t2[0] reusable) + f1(0) visible
  FF1C(1, t2[0])
  FF2C(0, t2[1])
  __syncthreads();   // bar4: f1(1) visible; f1(0) reads done before overwrite
  FF1C(2, t2[1])
  FF2C(1, t2[0])
  __syncthreads();   // bar5
  FF1C(3, t2[0])
  FF2C(2, t2[1])
  __syncthreads();   // bar6
  FF2C(3, t2[0])

  // ---- epilogue: out = x1(bf16) + C + b2 + 0.1*noise2 (inline) ----
  #pragma unroll
  for (int nt3 = 0; nt3 < 3; ++nt3) {
    int col = s*48 + nt3*16 + l15;
    float b2v = b2[col];
    #pragma unroll
    for (int r = 0; r < 4; ++r) {
      int row = rloc + r;
      uint32_t j = jbase + (uint32_t)row*96u + (uint32_t)col;
      uint32_t pk = ffp[nt3*2 + (r>>1)];
      float x1v = (r&1) ? bhi(pk) : blo(pk);
      out[(size_t)(rowbase + row)*96 + col] =
          x1v + acc2[nt3][r] + b2v + 0.1f * jax_normal(n2k0, n2k1, j);
    }
  }
  #undef FF2C
  #undef FF1C
  #undef BFRAG
}

// diagnostic fallback: ws too small -> zero out (absmax signature 5.125)
__global__ __launch_bounds__(256)
void k_zero(float* __restrict__ out)
{
  int i = blockIdx.x*256 + threadIdx.x;
  if (i < NTOK_) out[i] = 0.0f;
}

extern "C" void kernel_launch(void* const* d_in, const int* in_sizes, int n_in,
                              void* d_out, int out_size, void* d_ws, size_t ws_size,
                              hipStream_t stream) {
  const float* x    = (const float*)d_in[0];
  const float* Wq   = (const float*)d_in[1];
  const float* Wk   = (const float*)d_in[2];
  const float* Wv   = (const float*)d_in[3];
  const float* Wp   = (const float*)d_in[4];
  const float* bp   = (const float*)d_in[5];
  const float* g1   = (const float*)d_in[6];
  const float* bln1 = (const float*)d_in[7];
  const float* g2   = (const float*)d_in[8];
  const float* bln2 = (const float*)d_in[9];
  const float* W1   = (const float*)d_in[10];
  const float* b1   = (const float*)d_in[11];
  const float* W2   = (const float*)d_in[12];
  const float* b2   = (const float*)d_in[13];
  float* out = (float*)d_out;

  size_t need = (size_t)NTOK_*sizeof(bf16) + (size_t)WTOT_*sizeof(bf16);
  if (ws_size < need) {
    hipLaunchKernelGGL(k_zero, dim3((NTOK_ + 255)/256), dim3(256), 0, stream, out);
    return;
  }
  bf16* o_ws = (bf16*)d_ws;
  bf16* wbuf = o_ws + NTOK_;

  uint32_t n1k0 = 0u, n1k1 = 0u; tf2x32(0u, 42u, n1k0, n1k1);
  uint32_t n2k0 = 0u, n2k1 = 1u; tf2x32(0u, 42u, n2k0, n2k1);

  hipLaunchKernelGGL(k_attn_fused, dim3(B_*H_), dim3(256), 0, stream,
                     x, Wq, Wk, Wv, g1, bln1, o_ws, Wp, W1, W2, wbuf);
  hipLaunchKernelGGL(k_proj_ff, dim3(BT_/32), dim3(256), 0, stream,
                     x, o_ws, wbuf, bp, g2, bln2, b1, b2, out,
                     n1k0, n1k1, n2k0, n2k1);
}